// Round 2
// baseline (26.883 us; speedup 1.0000x reference)
//
#include <hip/hip_runtime.h>

// Problem constants (match reference)
#define BATCH 16
#define CHN   3
#define IMG_H 1024
#define IMG_W 2048
#define NPATCH 80
#define PSZ   16   // patch is 16x16

// One block per (b, patch); 256 threads = one per patch pixel; each thread
// produces all 3 channels (coords + index math shared across channels).
__global__ __launch_bounds__(256)
void TangentPlane_41644002902481_kernel(const float* __restrict__ x,
                                        const float* __restrict__ coords,
                                        float* __restrict__ out) {
    const int bid = blockIdx.x;        // b*NPATCH + patch
    const int tid = threadIdx.x;       // i*16 + j within the 16x16 patch

    const int patch = bid % NPATCH;
    const int b     = bid / NPATCH;

    // coords[patch, i, j, 0:2] — coalesced float2 load
    const float2 uv = reinterpret_cast<const float2*>(coords)[patch * (PSZ * PSZ) + tid];
    const float u = uv.x;
    const float v = uv.y;

    const float x0f = floorf(u);
    const float y0f = floorf(v);
    const float wu = u - x0f;
    const float wv = v - y0f;

    // Reference guarantees u in [0, W), v in [0, H-1]:
    //   x0 in [0, W-1] already; x1 wraps only at W-1. y0 in [0, H-1]; y1 clamps.
    const int x0 = (int)x0f;
    int x1 = x0 + 1; if (x1 >= IMG_W) x1 = 0;
    const int y0 = (int)y0f;
    const int y1 = min(y0 + 1, IMG_H - 1);

    const float w00 = (1.0f - wu) * (1.0f - wv);
    const float w01 = wu * (1.0f - wv);
    const float w10 = (1.0f - wu) * wv;
    const float w11 = wu * wv;

    const size_t off00 = (size_t)y0 * IMG_W + x0;
    const size_t off01 = (size_t)y0 * IMG_W + x1;
    const size_t off10 = (size_t)y1 * IMG_W + x0;
    const size_t off11 = (size_t)y1 * IMG_W + x1;

    const float* __restrict__ plane0 =
        x + (size_t)(b * CHN) * (size_t)(IMG_H * IMG_W);
    // out[b, patch, c*256 + tid]
    float* __restrict__ o0 = out + (size_t)bid * (CHN * PSZ * PSZ) + tid;

#pragma unroll
    for (int c = 0; c < CHN; ++c) {
        const float* __restrict__ plane = plane0 + (size_t)c * (IMG_H * IMG_W);
        const float g00 = plane[off00];
        const float g01 = plane[off01];
        const float g10 = plane[off10];
        const float g11 = plane[off11];
        o0[c * (PSZ * PSZ)] = g00 * w00 + g01 * w01 + g10 * w10 + g11 * w11;
    }
}

extern "C" void kernel_launch(void* const* d_in, const int* in_sizes, int n_in,
                              void* d_out, int out_size, void* d_ws, size_t ws_size,
                              hipStream_t stream) {
    const float* x      = (const float*)d_in[0];   // (16,3,1024,2048) fp32
    const float* coords = (const float*)d_in[1];   // (80,16,16,2) fp32
    float* out          = (float*)d_out;           // (16,80,768) fp32

    const int grid = BATCH * NPATCH;               // 1280 blocks
    TangentPlane_41644002902481_kernel<<<grid, 256, 0, stream>>>(x, coords, out);
}

// Round 3
// 26.649 us; speedup vs baseline: 1.0087x; 1.0087x over previous
//
#include <hip/hip_runtime.h>

// Problem constants (match reference)
#define BATCH 16
#define CHN   3
#define IMG_H 1024
#define IMG_W 2048
#define NPATCH 80
#define PSZ   16   // patch is 16x16

// One block per (b, patch); 256 threads = one per patch pixel; each thread
// produces all 3 channels. Pixel pairs (x0,x1) loaded as one unaligned
// float2 (gfx9+ global loads support unaligned access) except at the seam.
__global__ __launch_bounds__(256)
void TangentPlane_41644002902481_kernel(const float* __restrict__ x,
                                        const float* __restrict__ coords,
                                        float* __restrict__ out) {
    const int bid = blockIdx.x;        // b*NPATCH + patch
    const int tid = threadIdx.x;       // i*16 + j within the 16x16 patch

    const int patch = bid % NPATCH;
    const int b     = bid / NPATCH;

    // coords[patch, i, j, 0:2] — coalesced float2 load
    const float2 uv = reinterpret_cast<const float2*>(coords)[patch * (PSZ * PSZ) + tid];
    const float u = uv.x;
    const float v = uv.y;

    const float x0f = floorf(u);
    const float y0f = floorf(v);
    const float wu = u - x0f;
    const float wv = v - y0f;

    // Reference guarantees u in [0, W), v in [0, H-1]:
    //   x0 in [0, W-1]; x1 wraps only at W-1. y0 in [0, H-1]; y1 clamps.
    const int x0 = (int)x0f;
    const int y0 = (int)y0f;
    const int y1 = min(y0 + 1, IMG_H - 1);
    const bool wrap = (x0 == IMG_W - 1);

    const float w00 = (1.0f - wu) * (1.0f - wv);
    const float w01 = wu * (1.0f - wv);
    const float w10 = (1.0f - wu) * wv;
    const float w11 = wu * wv;

    const float* __restrict__ plane0 =
        x + (size_t)(b * CHN) * (size_t)(IMG_H * IMG_W);
    const size_t roff0 = (size_t)y0 * IMG_W;
    const size_t roff1 = (size_t)y1 * IMG_W;

    // out[b, patch, c*256 + tid]
    float* __restrict__ o0 = out + (size_t)bid * (CHN * PSZ * PSZ) + tid;

#pragma unroll
    for (int c = 0; c < CHN; ++c) {
        const float* __restrict__ plane = plane0 + (size_t)c * (IMG_H * IMG_W);
        const float* __restrict__ r0 = plane + roff0;
        const float* __restrict__ r1 = plane + roff1;
        float2 p0, p1;   // (g00,g01), (g10,g11)
        if (!wrap) {
            p0 = *reinterpret_cast<const float2*>(r0 + x0);
            p1 = *reinterpret_cast<const float2*>(r1 + x0);
        } else {
            p0 = make_float2(r0[IMG_W - 1], r0[0]);
            p1 = make_float2(r1[IMG_W - 1], r1[0]);
        }
        o0[c * (PSZ * PSZ)] = p0.x * w00 + p0.y * w01 + p1.x * w10 + p1.y * w11;
    }
}

extern "C" void kernel_launch(void* const* d_in, const int* in_sizes, int n_in,
                              void* d_out, int out_size, void* d_ws, size_t ws_size,
                              hipStream_t stream) {
    const float* x      = (const float*)d_in[0];   // (16,3,1024,2048) fp32
    const float* coords = (const float*)d_in[1];   // (80,16,16,2) fp32
    float* out          = (float*)d_out;           // (16,80,768) fp32

    const int grid = BATCH * NPATCH;               // 1280 blocks
    TangentPlane_41644002902481_kernel<<<grid, 256, 0, stream>>>(x, coords, out);
}